// Round 2
// baseline (1264.308 us; speedup 1.0000x reference)
//
#include <hip/hip_runtime.h>
#include <math.h>

#define N_USERS 50000
#define N_ITEMS 50000
#define N_NODES 100000
#define N_NODES_PAD 100032
#define EMB 64
#define N_LAYERS 3
#define N_EDGES 1600000
#define BATCH 16384
#define REG_C 1e-05f
#define SLOPE 0.01f
#define EPS_C 1e-12f

#define SCAN_CHUNK 256
#define NCHUNK ((N_NODES + SCAN_CHUNK - 1) / SCAN_CHUNK)   // 391

// ---------------- ego init: concat(u_emb, i_emb) ----------------
__global__ void k_init_ego(const float* __restrict__ u_emb,
                           const float* __restrict__ i_emb,
                           float* __restrict__ ego) {
    int idx = blockIdx.x * blockDim.x + threadIdx.x;   // float4 index
    const int n4 = N_NODES * EMB / 4;
    if (idx < n4) {
        const int u4 = N_USERS * EMB / 4;
        float4 v = (idx < u4) ? ((const float4*)u_emb)[idx]
                              : ((const float4*)i_emb)[idx - u4];
        ((float4*)ego)[idx] = v;
    }
}

// ---------------- CSR build ----------------
__global__ void k_histo(const int* __restrict__ rows, int* __restrict__ counts) {
    int e = blockIdx.x * blockDim.x + threadIdx.x;
    if (e < N_EDGES) atomicAdd(&counts[rows[e]], 1);
}

__global__ void k_chunk_sum(const int* __restrict__ counts, int* __restrict__ partials) {
    __shared__ int s[SCAN_CHUNK];
    int i = blockIdx.x * SCAN_CHUNK + threadIdx.x;
    int v = (i < N_NODES) ? counts[i] : 0;
    s[threadIdx.x] = v;
    __syncthreads();
    for (int st = SCAN_CHUNK / 2; st > 0; st >>= 1) {
        if ((int)threadIdx.x < st) s[threadIdx.x] += s[threadIdx.x + st];
        __syncthreads();
    }
    if (threadIdx.x == 0) partials[blockIdx.x] = s[0];
}

__global__ void k_scan_partials(int* __restrict__ partials) {
    __shared__ int s[512];
    int t = threadIdx.x;
    int v = (t < NCHUNK) ? partials[t] : 0;
    s[t] = v;
    __syncthreads();
    for (int st = 1; st < 512; st <<= 1) {
        int add = (t >= st) ? s[t - st] : 0;
        __syncthreads();
        s[t] += add;
        __syncthreads();
    }
    if (t < NCHUNK) partials[t] = s[t] - v;   // exclusive
}

__global__ void k_chunk_scan(const int* __restrict__ counts,
                             const int* __restrict__ partials,
                             int* __restrict__ offsets,
                             int* __restrict__ cursor) {
    __shared__ int s[SCAN_CHUNK];
    int t = threadIdx.x;
    int i = blockIdx.x * SCAN_CHUNK + t;
    int v = (i < N_NODES) ? counts[i] : 0;
    s[t] = v;
    __syncthreads();
    for (int st = 1; st < SCAN_CHUNK; st <<= 1) {
        int add = (t >= st) ? s[t - st] : 0;
        __syncthreads();
        s[t] += add;
        __syncthreads();
    }
    int excl = s[t] - v + partials[blockIdx.x];
    if (i < N_NODES) { offsets[i] = excl; cursor[i] = excl; }
    if (blockIdx.x == 0 && t == 0) offsets[N_NODES] = N_EDGES;
}

__global__ void k_scatter(const int* __restrict__ rows, const int* __restrict__ cols,
                          const float* __restrict__ vals,
                          int* __restrict__ cursor,
                          int2* __restrict__ edge_cv) {
    int e = blockIdx.x * blockDim.x + threadIdx.x;
    if (e < N_EDGES) {
        int r = rows[e];
        int pos = atomicAdd(&cursor[r], 1);
        edge_cv[pos] = make_int2(cols[e], __float_as_int(vals[e]));
    }
}

// ---------------- per-layer: gather-based segment sum, 4 nodes / wave ----------------
__global__ __launch_bounds__(256) void k_edge_agg(const int* __restrict__ offsets,
                                                  const int2* __restrict__ edge_cv,
                                                  const float* __restrict__ ego,
                                                  float* __restrict__ wsacc) {
    int wid  = (blockIdx.x * blockDim.x + threadIdx.x) >> 6;
    int lane = threadIdx.x & 63;
    int base = wid * 4;
    if (base >= N_NODES) return;
    int o0 = offsets[base], o1 = offsets[base + 1], o2 = offsets[base + 2];
    int o3 = offsets[base + 3], o4 = offsets[base + 4];
    int n0 = o1 - o0, n1 = o2 - o1, n2 = o3 - o2, n3 = o4 - o3;
    int mx = max(max(n0, n1), max(n2, n3));
    float a0 = 0.f, a1 = 0.f, a2 = 0.f, a3 = 0.f;
    for (int t = 0; t < mx; ++t) {
        // four independent chains; branches are wave-uniform (no divergence)
        if (t < n0) { int2 cv = edge_cv[o0 + t]; a0 += __int_as_float(cv.y) * ego[(size_t)cv.x * EMB + lane]; }
        if (t < n1) { int2 cv = edge_cv[o1 + t]; a1 += __int_as_float(cv.y) * ego[(size_t)cv.x * EMB + lane]; }
        if (t < n2) { int2 cv = edge_cv[o2 + t]; a2 += __int_as_float(cv.y) * ego[(size_t)cv.x * EMB + lane]; }
        if (t < n3) { int2 cv = edge_cv[o3 + t]; a3 += __int_as_float(cv.y) * ego[(size_t)cv.x * EMB + lane]; }
    }
    size_t g = (size_t)base * EMB + lane;
    wsacc[g]           = a0;
    wsacc[g + EMB]     = a1;
    wsacc[g + 2 * EMB] = a2;
    wsacc[g + 3 * EMB] = a3;
}

// ---------------- per-layer transform: tiled f32 GEMM ----------------
// t = [ws | ws*ego] @ [W1^T ; W2^T] + b1 + b2 ; leaky-relu -> ego
// BM=64 rows/block, all 64 cols, K=128 split in two 64-phases.
__global__ __launch_bounds__(256) void k_transform(const float* __restrict__ wsacc,
                                                   float* __restrict__ ego,
                                                   const float* __restrict__ W1,
                                                   const float* __restrict__ b1,
                                                   const float* __restrict__ W2,
                                                   const float* __restrict__ b2) {
    __shared__ float Xs[64 * 64];    // [r][k'] swizzled, one K-half at a time
    __shared__ float Ws[64 * 128];   // [c][kk'] swizzled, kk = 0..127 (W1 | W2)
    int tid = threadIdx.x;

    // stage Wcat: Ws[c][k] = W1[c][k], Ws[c][64+k] = W2[c][k]; swizzle k' = k ^ ((c>>2 & 7)<<2)
    for (int idx = tid; idx < 4096; idx += 256) {
        int c = idx >> 6, k = idx & 63;
        int s = ((c >> 2) & 7) << 2;
        Ws[c * 128 + (k ^ s)]        = W1[idx];
        Ws[c * 128 + 64 + (k ^ s)]   = W2[idx];   // (64+k)^s == 64 + (k^s)
    }

    int lane = tid & 63, wv = tid >> 6;
    int r0 = blockIdx.x * 64;
    int ty = tid >> 4;       // 0..15 : owns rows ty*4 .. ty*4+3
    int tx = tid & 15;       // 0..15 : owns cols tx*4 .. tx*4+3
    int sa = (ty & 7) << 2;  // row swizzle: (r>>2)&7 == ty&7 for r = ty*4+i
    int sb = (tx & 7) << 2;  // col-row swizzle for Ws rows c = tx*4+j: (c>>2)&7 == tx&7

    float acc[4][4] = {};

    // ---- phase A: k = 0..63 with X = ws ----
    for (int r = wv; r < 64; r += 4) {
        float wsv = wsacc[(size_t)(r0 + r) * EMB + lane];
        int s = ((r >> 2) & 7) << 2;
        Xs[r * 64 + (lane ^ s)] = wsv;
    }
    __syncthreads();
    #pragma unroll
    for (int ko = 0; ko < 64; ko += 4) {
        float4 a[4], b[4];
        #pragma unroll
        for (int i = 0; i < 4; ++i)
            a[i] = *(const float4*)&Xs[(ty * 4 + i) * 64 + (ko ^ sa)];
        #pragma unroll
        for (int j = 0; j < 4; ++j)
            b[j] = *(const float4*)&Ws[(tx * 4 + j) * 128 + (ko ^ sb)];
        #pragma unroll
        for (int i = 0; i < 4; ++i)
            #pragma unroll
            for (int j = 0; j < 4; ++j)
                acc[i][j] += a[i].x * b[j].x + a[i].y * b[j].y
                           + a[i].z * b[j].z + a[i].w * b[j].w;
    }
    __syncthreads();

    // ---- phase B: k = 64..127 with X = ws*ego ----
    for (int r = wv; r < 64; r += 4) {
        size_t g = (size_t)(r0 + r) * EMB + lane;
        float v = wsacc[g] * ego[g];
        int s = ((r >> 2) & 7) << 2;
        Xs[r * 64 + (lane ^ s)] = v;
    }
    __syncthreads();
    #pragma unroll
    for (int ko = 0; ko < 64; ko += 4) {
        float4 a[4], b[4];
        #pragma unroll
        for (int i = 0; i < 4; ++i)
            a[i] = *(const float4*)&Xs[(ty * 4 + i) * 64 + (ko ^ sa)];
        #pragma unroll
        for (int j = 0; j < 4; ++j)
            b[j] = *(const float4*)&Ws[(tx * 4 + j) * 128 + 64 + (ko ^ sb)];
        #pragma unroll
        for (int i = 0; i < 4; ++i)
            #pragma unroll
            for (int j = 0; j < 4; ++j)
                acc[i][j] += a[i].x * b[j].x + a[i].y * b[j].y
                           + a[i].z * b[j].z + a[i].w * b[j].w;
    }

    // ---- epilogue: bias + leaky, write ego ----
    float4 bb1 = *(const float4*)&b1[tx * 4];
    float4 bb2 = *(const float4*)&b2[tx * 4];
    float bias[4] = { bb1.x + bb2.x, bb1.y + bb2.y, bb1.z + bb2.z, bb1.w + bb2.w };
    #pragma unroll
    for (int i = 0; i < 4; ++i) {
        int r = r0 + ty * 4 + i;   // < N_NODES_PAD, buffer padded -> no guard
        float4 o;
        float t0 = acc[i][0] + bias[0]; o.x = (t0 >= 0.f) ? t0 : SLOPE * t0;
        float t1 = acc[i][1] + bias[1]; o.y = (t1 >= 0.f) ? t1 : SLOPE * t1;
        float t2 = acc[i][2] + bias[2]; o.z = (t2 >= 0.f) ? t2 : SLOPE * t2;
        float t3 = acc[i][3] + bias[3]; o.w = (t3 >= 0.f) ? t3 : SLOPE * t3;
        *(float4*)&ego[(size_t)r * EMB + tx * 4] = o;
    }
}

// ---------------- per-layer: batch gather + partial-loss accumulation ----------------
// acc layout: [0]=dot_up, [1]=dot_un, [2]=ssq_u, [3]=ssq_p, [4]=ssq_n ; each [BATCH]
__global__ __launch_bounds__(256) void k_batch_acc(const float* __restrict__ src,
                                                   const int* __restrict__ u,
                                                   const int* __restrict__ ii,
                                                   const int* __restrict__ jj,
                                                   float* __restrict__ acc,
                                                   int normalize) {
    int wid = (blockIdx.x * blockDim.x + threadIdx.x) >> 6;
    int lane = threadIdx.x & 63;
    if (wid >= BATCH) return;
    int nu = u[wid];
    int np_ = N_USERS + ii[wid];
    int nn = N_USERS + jj[wid];
    float eu = src[(size_t)nu * EMB + lane];
    float ep = src[(size_t)np_ * EMB + lane];
    float en = src[(size_t)nn * EMB + lane];
    float d_up = eu * ep, d_un = eu * en;
    float s_u = eu * eu, s_p = ep * ep, s_n = en * en;
    #pragma unroll
    for (int m = 32; m > 0; m >>= 1) {
        d_up += __shfl_xor(d_up, m, 64);
        d_un += __shfl_xor(d_un, m, 64);
        s_u  += __shfl_xor(s_u,  m, 64);
        s_p  += __shfl_xor(s_p,  m, 64);
        s_n  += __shfl_xor(s_n,  m, 64);
    }
    if (lane == 0) {
        if (normalize) {
            float inu = 1.f / fmaxf(sqrtf(s_u), EPS_C);
            float inp = 1.f / fmaxf(sqrtf(s_p), EPS_C);
            float inn = 1.f / fmaxf(sqrtf(s_n), EPS_C);
            d_up *= inu * inp;
            d_un *= inu * inn;
            s_u *= inu * inu;
            s_p *= inp * inp;
            s_n *= inn * inn;
        }
        acc[0 * BATCH + wid] += d_up;
        acc[1 * BATCH + wid] += d_un;
        acc[2 * BATCH + wid] += s_u;
        acc[3 * BATCH + wid] += s_p;
        acc[4 * BATCH + wid] += s_n;
    }
}

// ---------------- final scalar ----------------
__global__ __launch_bounds__(1024) void k_finalize(const float* __restrict__ acc,
                                                   float* __restrict__ out) {
    __shared__ float s1[1024], s2[1024];
    float ls = 0.f, l2 = 0.f;
    for (int b = threadIdx.x; b < BATCH; b += 1024) {
        float x = acc[0 * BATCH + b] - acc[1 * BATCH + b];
        ls += fminf(x, 0.f) - log1pf(expf(-fabsf(x)));
        l2 += acc[2 * BATCH + b] + acc[3 * BATCH + b] + acc[4 * BATCH + b];
    }
    s1[threadIdx.x] = ls; s2[threadIdx.x] = l2;
    __syncthreads();
    for (int st = 512; st > 0; st >>= 1) {
        if ((int)threadIdx.x < st) {
            s1[threadIdx.x] += s1[threadIdx.x + st];
            s2[threadIdx.x] += s2[threadIdx.x + st];
        }
        __syncthreads();
    }
    if (threadIdx.x == 0)
        out[0] = -s1[0] / (float)BATCH + REG_C * (s2[0] * 0.5f) / (float)BATCH;
}

extern "C" void kernel_launch(void* const* d_in, const int* in_sizes, int n_in,
                              void* d_out, int out_size, void* d_ws, size_t ws_size,
                              hipStream_t stream) {
    (void)in_sizes; (void)n_in; (void)out_size; (void)ws_size;
    const int*   u     = (const int*)d_in[0];
    const int*   ii    = (const int*)d_in[1];
    const int*   jj    = (const int*)d_in[2];
    const int*   rows  = (const int*)d_in[3];
    const int*   cols  = (const int*)d_in[4];
    const float* vals  = (const float*)d_in[5];
    const float* u_emb = (const float*)d_in[6];
    const float* i_emb = (const float*)d_in[7];
    const float* W1_w  = (const float*)d_in[8];
    const float* W1_b  = (const float*)d_in[9];
    const float* W2_w  = (const float*)d_in[10];
    const float* W2_b  = (const float*)d_in[11];
    float* out = (float*)d_out;

    // workspace carve-up (rows padded to N_NODES_PAD so transform tail needs no guards)
    char* p = (char*)d_ws;
    float* ego      = (float*)p;  p += (size_t)N_NODES_PAD * EMB * 4;
    float* wsacc    = (float*)p;  p += (size_t)N_NODES_PAD * EMB * 4;
    int2*  edge_cv  = (int2*)p;   p += (size_t)N_EDGES * 8;
    int*   counts   = (int*)p;    p += (size_t)N_NODES * 4;
    int*   offsets  = (int*)p;    p += (size_t)(N_NODES + 1) * 4;
    int*   cursor   = (int*)p;    p += (size_t)N_NODES * 4;
    int*   partials = (int*)p;    p += 512 * 4;
    float* acc      = (float*)p;  p += (size_t)5 * BATCH * 4;

    hipMemsetAsync(counts, 0, (size_t)N_NODES * 4, stream);
    hipMemsetAsync(acc, 0, (size_t)5 * BATCH * 4, stream);

    k_init_ego<<<(N_NODES * EMB / 4 + 255) / 256, 256, 0, stream>>>(u_emb, i_emb, ego);
    k_histo<<<(N_EDGES + 255) / 256, 256, 0, stream>>>(rows, counts);
    k_chunk_sum<<<NCHUNK, SCAN_CHUNK, 0, stream>>>(counts, partials);
    k_scan_partials<<<1, 512, 0, stream>>>(partials);
    k_chunk_scan<<<NCHUNK, SCAN_CHUNK, 0, stream>>>(counts, partials, offsets, cursor);
    k_scatter<<<(N_EDGES + 255) / 256, 256, 0, stream>>>(rows, cols, vals, cursor, edge_cv);

    // layer 0 contribution (raw ego, no normalization)
    k_batch_acc<<<BATCH * 64 / 256, 256, 0, stream>>>(ego, u, ii, jj, acc, 0);

    for (int k = 0; k < N_LAYERS; ++k) {
        k_edge_agg<<<(N_NODES / 4 * 64 + 255) / 256, 256, 0, stream>>>(offsets, edge_cv, ego, wsacc);
        k_transform<<<(N_NODES + 63) / 64, 256, 0, stream>>>(wsacc, ego,
                                              W1_w + k * 4096, W1_b + k * 64,
                                              W2_w + k * 4096, W2_b + k * 64);
        k_batch_acc<<<BATCH * 64 / 256, 256, 0, stream>>>(ego, u, ii, jj, acc, 1);
    }
    k_finalize<<<1, 1024, 0, stream>>>(acc, out);
}

// Round 3
// 881.033 us; speedup vs baseline: 1.4350x; 1.4350x over previous
//
#include <hip/hip_runtime.h>
#include <math.h>

#define N_USERS 50000
#define N_ITEMS 50000
#define N_NODES 100000
#define N_NODES_PAD 100032
#define EMB 64
#define N_LAYERS 3
#define N_EDGES 1600000
#define BATCH 16384
#define REG_C 1e-05f
#define SLOPE 0.01f
#define EPS_C 1e-12f

#define SCAN_CHUNK 256
#define NCHUNK ((N_NODES + SCAN_CHUNK - 1) / SCAN_CHUNK)   // 391

// ---------------- ego init: concat(u_emb, i_emb) ----------------
__global__ void k_init_ego(const float* __restrict__ u_emb,
                           const float* __restrict__ i_emb,
                           float* __restrict__ ego) {
    int idx = blockIdx.x * blockDim.x + threadIdx.x;   // float4 index
    const int n4 = N_NODES * EMB / 4;
    if (idx < n4) {
        const int u4 = N_USERS * EMB / 4;
        float4 v = (idx < u4) ? ((const float4*)u_emb)[idx]
                              : ((const float4*)i_emb)[idx - u4];
        ((float4*)ego)[idx] = v;
    }
}

// ---------------- CSR build ----------------
__global__ void k_histo(const int* __restrict__ rows, int* __restrict__ counts) {
    int e = blockIdx.x * blockDim.x + threadIdx.x;
    if (e < N_EDGES) atomicAdd(&counts[rows[e]], 1);
}

__global__ void k_chunk_sum(const int* __restrict__ counts, int* __restrict__ partials) {
    __shared__ int s[SCAN_CHUNK];
    int i = blockIdx.x * SCAN_CHUNK + threadIdx.x;
    int v = (i < N_NODES) ? counts[i] : 0;
    s[threadIdx.x] = v;
    __syncthreads();
    for (int st = SCAN_CHUNK / 2; st > 0; st >>= 1) {
        if ((int)threadIdx.x < st) s[threadIdx.x] += s[threadIdx.x + st];
        __syncthreads();
    }
    if (threadIdx.x == 0) partials[blockIdx.x] = s[0];
}

__global__ void k_scan_partials(int* __restrict__ partials) {
    __shared__ int s[512];
    int t = threadIdx.x;
    int v = (t < NCHUNK) ? partials[t] : 0;
    s[t] = v;
    __syncthreads();
    for (int st = 1; st < 512; st <<= 1) {
        int add = (t >= st) ? s[t - st] : 0;
        __syncthreads();
        s[t] += add;
        __syncthreads();
    }
    if (t < NCHUNK) partials[t] = s[t] - v;   // exclusive
}

__global__ void k_chunk_scan(const int* __restrict__ counts,
                             const int* __restrict__ partials,
                             int* __restrict__ offsets,
                             int* __restrict__ cursor) {
    __shared__ int s[SCAN_CHUNK];
    int t = threadIdx.x;
    int i = blockIdx.x * SCAN_CHUNK + t;
    int v = (i < N_NODES) ? counts[i] : 0;
    s[t] = v;
    __syncthreads();
    for (int st = 1; st < SCAN_CHUNK; st <<= 1) {
        int add = (t >= st) ? s[t - st] : 0;
        __syncthreads();
        s[t] += add;
        __syncthreads();
    }
    int excl = s[t] - v + partials[blockIdx.x];
    if (i < N_NODES) { offsets[i] = excl; cursor[i] = excl; }
    if (blockIdx.x == 0 && t == 0) offsets[N_NODES] = N_EDGES;
}

__global__ void k_scatter(const int* __restrict__ rows, const int* __restrict__ cols,
                          const float* __restrict__ vals,
                          int* __restrict__ cursor,
                          int2* __restrict__ edge_cv) {
    int e = blockIdx.x * blockDim.x + threadIdx.x;
    if (e < N_EDGES) {
        int r = rows[e];
        int pos = atomicAdd(&cursor[r], 1);
        edge_cv[pos] = make_int2(cols[e], __float_as_int(vals[e]));
    }
}

// ---------------- per-layer: gather-based segment sum, 4 nodes / wave ----------------
__global__ __launch_bounds__(256) void k_edge_agg(const int* __restrict__ offsets,
                                                  const int2* __restrict__ edge_cv,
                                                  const float* __restrict__ ego,
                                                  float* __restrict__ wsacc) {
    int wid  = (blockIdx.x * blockDim.x + threadIdx.x) >> 6;
    int lane = threadIdx.x & 63;
    int base = wid * 4;
    if (base >= N_NODES) return;
    int o0 = offsets[base], o1 = offsets[base + 1], o2 = offsets[base + 2];
    int o3 = offsets[base + 3], o4 = offsets[base + 4];
    int n0 = o1 - o0, n1 = o2 - o1, n2 = o3 - o2, n3 = o4 - o3;
    int mx = max(max(n0, n1), max(n2, n3));
    float a0 = 0.f, a1 = 0.f, a2 = 0.f, a3 = 0.f;
    for (int t = 0; t < mx; ++t) {
        // four independent chains; branches are wave-uniform (no divergence)
        if (t < n0) { int2 cv = edge_cv[o0 + t]; a0 += __int_as_float(cv.y) * ego[(size_t)cv.x * EMB + lane]; }
        if (t < n1) { int2 cv = edge_cv[o1 + t]; a1 += __int_as_float(cv.y) * ego[(size_t)cv.x * EMB + lane]; }
        if (t < n2) { int2 cv = edge_cv[o2 + t]; a2 += __int_as_float(cv.y) * ego[(size_t)cv.x * EMB + lane]; }
        if (t < n3) { int2 cv = edge_cv[o3 + t]; a3 += __int_as_float(cv.y) * ego[(size_t)cv.x * EMB + lane]; }
    }
    size_t g = (size_t)base * EMB + lane;
    wsacc[g]           = a0;
    wsacc[g + EMB]     = a1;
    wsacc[g + 2 * EMB] = a2;
    wsacc[g + 3 * EMB] = a3;
}

// ---------------- per-layer transform: tiled f32 GEMM ----------------
// t = [ws | ws*ego] @ [W1^T ; W2^T] + b1 + b2 ; leaky-relu -> ego
// BM=64 rows/block, all 64 cols, K=128 split in two 64-phases.
// __launch_bounds__(256,3): cap VGPR ~168 so the K-loop (unroll 2) cannot spill;
// LDS 48KB -> 3 blocks/CU, matching.
__global__ __launch_bounds__(256, 3) void k_transform(const float* __restrict__ wsacc,
                                                      float* __restrict__ ego,
                                                      const float* __restrict__ W1,
                                                      const float* __restrict__ b1,
                                                      const float* __restrict__ W2,
                                                      const float* __restrict__ b2) {
    __shared__ float Xs[64 * 64];    // [r][k'] swizzled, one K-half at a time
    __shared__ float Ws[64 * 128];   // [c][kk'] swizzled, kk = 0..127 (W1 | W2)
    int tid = threadIdx.x;

    // stage Wcat: Ws[c][k] = W1[c][k], Ws[c][64+k] = W2[c][k]; swizzle k' = k ^ ((c>>2 & 7)<<2)
    for (int idx = tid; idx < 4096; idx += 256) {
        int c = idx >> 6, k = idx & 63;
        int s = ((c >> 2) & 7) << 2;
        Ws[c * 128 + (k ^ s)]        = W1[idx];
        Ws[c * 128 + 64 + (k ^ s)]   = W2[idx];   // (64+k)^s == 64 + (k^s)
    }

    int lane = tid & 63, wv = tid >> 6;
    int r0 = blockIdx.x * 64;
    int ty = tid >> 4;       // 0..15 : owns rows ty*4 .. ty*4+3
    int tx = tid & 15;       // 0..15 : owns cols tx*4 .. tx*4+3
    int sa = (ty & 7) << 2;  // row swizzle: (r>>2)&7 == ty&7 for r = ty*4+i
    int sb = (tx & 7) << 2;  // col-row swizzle for Ws rows c = tx*4+j

    float acc[4][4] = {};

    // ---- phase A: k = 0..63 with X = ws ----
    for (int r = wv; r < 64; r += 4) {
        float wsv = wsacc[(size_t)(r0 + r) * EMB + lane];
        int s = ((r >> 2) & 7) << 2;
        Xs[r * 64 + (lane ^ s)] = wsv;
    }
    __syncthreads();
    #pragma unroll 2
    for (int ko = 0; ko < 64; ko += 4) {
        float4 a[4], b[4];
        #pragma unroll
        for (int i = 0; i < 4; ++i)
            a[i] = *(const float4*)&Xs[(ty * 4 + i) * 64 + (ko ^ sa)];
        #pragma unroll
        for (int j = 0; j < 4; ++j)
            b[j] = *(const float4*)&Ws[(tx * 4 + j) * 128 + (ko ^ sb)];
        #pragma unroll
        for (int i = 0; i < 4; ++i)
            #pragma unroll
            for (int j = 0; j < 4; ++j)
                acc[i][j] += a[i].x * b[j].x + a[i].y * b[j].y
                           + a[i].z * b[j].z + a[i].w * b[j].w;
    }
    __syncthreads();

    // ---- phase B: k = 64..127 with X = ws*ego ----
    for (int r = wv; r < 64; r += 4) {
        size_t g = (size_t)(r0 + r) * EMB + lane;
        float v = wsacc[g] * ego[g];
        int s = ((r >> 2) & 7) << 2;
        Xs[r * 64 + (lane ^ s)] = v;
    }
    __syncthreads();
    #pragma unroll 2
    for (int ko = 0; ko < 64; ko += 4) {
        float4 a[4], b[4];
        #pragma unroll
        for (int i = 0; i < 4; ++i)
            a[i] = *(const float4*)&Xs[(ty * 4 + i) * 64 + (ko ^ sa)];
        #pragma unroll
        for (int j = 0; j < 4; ++j)
            b[j] = *(const float4*)&Ws[(tx * 4 + j) * 128 + 64 + (ko ^ sb)];
        #pragma unroll
        for (int i = 0; i < 4; ++i)
            #pragma unroll
            for (int j = 0; j < 4; ++j)
                acc[i][j] += a[i].x * b[j].x + a[i].y * b[j].y
                           + a[i].z * b[j].z + a[i].w * b[j].w;
    }

    // ---- epilogue: bias + leaky, write ego ----
    float4 bb1 = *(const float4*)&b1[tx * 4];
    float4 bb2 = *(const float4*)&b2[tx * 4];
    float bias[4] = { bb1.x + bb2.x, bb1.y + bb2.y, bb1.z + bb2.z, bb1.w + bb2.w };
    #pragma unroll
    for (int i = 0; i < 4; ++i) {
        int r = r0 + ty * 4 + i;   // < N_NODES_PAD, buffer padded -> no guard
        float4 o;
        float t0 = acc[i][0] + bias[0]; o.x = (t0 >= 0.f) ? t0 : SLOPE * t0;
        float t1 = acc[i][1] + bias[1]; o.y = (t1 >= 0.f) ? t1 : SLOPE * t1;
        float t2 = acc[i][2] + bias[2]; o.z = (t2 >= 0.f) ? t2 : SLOPE * t2;
        float t3 = acc[i][3] + bias[3]; o.w = (t3 >= 0.f) ? t3 : SLOPE * t3;
        *(float4*)&ego[(size_t)r * EMB + tx * 4] = o;
    }
}

// ---------------- per-layer: batch gather + partial-loss accumulation ----------------
// acc layout: [0]=dot_up, [1]=dot_un, [2]=ssq_u, [3]=ssq_p, [4]=ssq_n ; each [BATCH]
__global__ __launch_bounds__(256) void k_batch_acc(const float* __restrict__ src,
                                                   const int* __restrict__ u,
                                                   const int* __restrict__ ii,
                                                   const int* __restrict__ jj,
                                                   float* __restrict__ acc,
                                                   int normalize) {
    int wid = (blockIdx.x * blockDim.x + threadIdx.x) >> 6;
    int lane = threadIdx.x & 63;
    if (wid >= BATCH) return;
    int nu = u[wid];
    int np_ = N_USERS + ii[wid];
    int nn = N_USERS + jj[wid];
    float eu = src[(size_t)nu * EMB + lane];
    float ep = src[(size_t)np_ * EMB + lane];
    float en = src[(size_t)nn * EMB + lane];
    float d_up = eu * ep, d_un = eu * en;
    float s_u = eu * eu, s_p = ep * ep, s_n = en * en;
    #pragma unroll
    for (int m = 32; m > 0; m >>= 1) {
        d_up += __shfl_xor(d_up, m, 64);
        d_un += __shfl_xor(d_un, m, 64);
        s_u  += __shfl_xor(s_u,  m, 64);
        s_p  += __shfl_xor(s_p,  m, 64);
        s_n  += __shfl_xor(s_n,  m, 64);
    }
    if (lane == 0) {
        if (normalize) {
            float inu = 1.f / fmaxf(sqrtf(s_u), EPS_C);
            float inp = 1.f / fmaxf(sqrtf(s_p), EPS_C);
            float inn = 1.f / fmaxf(sqrtf(s_n), EPS_C);
            d_up *= inu * inp;
            d_un *= inu * inn;
            s_u *= inu * inu;
            s_p *= inp * inp;
            s_n *= inn * inn;
        }
        acc[0 * BATCH + wid] += d_up;
        acc[1 * BATCH + wid] += d_un;
        acc[2 * BATCH + wid] += s_u;
        acc[3 * BATCH + wid] += s_p;
        acc[4 * BATCH + wid] += s_n;
    }
}

// ---------------- final scalar ----------------
__global__ __launch_bounds__(1024) void k_finalize(const float* __restrict__ acc,
                                                   float* __restrict__ out) {
    __shared__ float s1[1024], s2[1024];
    float ls = 0.f, l2 = 0.f;
    for (int b = threadIdx.x; b < BATCH; b += 1024) {
        float x = acc[0 * BATCH + b] - acc[1 * BATCH + b];
        ls += fminf(x, 0.f) - log1pf(expf(-fabsf(x)));
        l2 += acc[2 * BATCH + b] + acc[3 * BATCH + b] + acc[4 * BATCH + b];
    }
    s1[threadIdx.x] = ls; s2[threadIdx.x] = l2;
    __syncthreads();
    for (int st = 512; st > 0; st >>= 1) {
        if ((int)threadIdx.x < st) {
            s1[threadIdx.x] += s1[threadIdx.x + st];
            s2[threadIdx.x] += s2[threadIdx.x + st];
        }
        __syncthreads();
    }
    if (threadIdx.x == 0)
        out[0] = -s1[0] / (float)BATCH + REG_C * (s2[0] * 0.5f) / (float)BATCH;
}

extern "C" void kernel_launch(void* const* d_in, const int* in_sizes, int n_in,
                              void* d_out, int out_size, void* d_ws, size_t ws_size,
                              hipStream_t stream) {
    (void)in_sizes; (void)n_in; (void)out_size; (void)ws_size;
    const int*   u     = (const int*)d_in[0];
    const int*   ii    = (const int*)d_in[1];
    const int*   jj    = (const int*)d_in[2];
    const int*   rows  = (const int*)d_in[3];
    const int*   cols  = (const int*)d_in[4];
    const float* vals  = (const float*)d_in[5];
    const float* u_emb = (const float*)d_in[6];
    const float* i_emb = (const float*)d_in[7];
    const float* W1_w  = (const float*)d_in[8];
    const float* W1_b  = (const float*)d_in[9];
    const float* W2_w  = (const float*)d_in[10];
    const float* W2_b  = (const float*)d_in[11];
    float* out = (float*)d_out;

    // workspace carve-up (rows padded to N_NODES_PAD so transform tail needs no guards)
    char* p = (char*)d_ws;
    float* ego      = (float*)p;  p += (size_t)N_NODES_PAD * EMB * 4;
    float* wsacc    = (float*)p;  p += (size_t)N_NODES_PAD * EMB * 4;
    int2*  edge_cv  = (int2*)p;   p += (size_t)N_EDGES * 8;
    int*   counts   = (int*)p;    p += (size_t)N_NODES * 4;
    int*   offsets  = (int*)p;    p += (size_t)(N_NODES + 1) * 4;
    int*   cursor   = (int*)p;    p += (size_t)N_NODES * 4;
    int*   partials = (int*)p;    p += 512 * 4;
    float* acc      = (float*)p;  p += (size_t)5 * BATCH * 4;

    hipMemsetAsync(counts, 0, (size_t)N_NODES * 4, stream);
    hipMemsetAsync(acc, 0, (size_t)5 * BATCH * 4, stream);

    k_init_ego<<<(N_NODES * EMB / 4 + 255) / 256, 256, 0, stream>>>(u_emb, i_emb, ego);
    k_histo<<<(N_EDGES + 255) / 256, 256, 0, stream>>>(rows, counts);
    k_chunk_sum<<<NCHUNK, SCAN_CHUNK, 0, stream>>>(counts, partials);
    k_scan_partials<<<1, 512, 0, stream>>>(partials);
    k_chunk_scan<<<NCHUNK, SCAN_CHUNK, 0, stream>>>(counts, partials, offsets, cursor);
    k_scatter<<<(N_EDGES + 255) / 256, 256, 0, stream>>>(rows, cols, vals, cursor, edge_cv);

    // layer 0 contribution (raw ego, no normalization)
    k_batch_acc<<<BATCH * 64 / 256, 256, 0, stream>>>(ego, u, ii, jj, acc, 0);

    for (int k = 0; k < N_LAYERS; ++k) {
        k_edge_agg<<<(N_NODES / 4 * 64 + 255) / 256, 256, 0, stream>>>(offsets, edge_cv, ego, wsacc);
        k_transform<<<(N_NODES + 63) / 64, 256, 0, stream>>>(wsacc, ego,
                                              W1_w + k * 4096, W1_b + k * 64,
                                              W2_w + k * 4096, W2_b + k * 64);
        k_batch_acc<<<BATCH * 64 / 256, 256, 0, stream>>>(ego, u, ii, jj, acc, 1);
    }
    k_finalize<<<1, 1024, 0, stream>>>(acc, out);
}

// Round 4
// 563.198 us; speedup vs baseline: 2.2449x; 1.5643x over previous
//
#include <hip/hip_runtime.h>
#include <math.h>

#define N_USERS 50000
#define N_ITEMS 50000
#define N_NODES 100000
#define N_NODES_PAD 100032
#define EMB 64
#define N_LAYERS 3
#define N_EDGES 1600000
#define BATCH 16384
#define REG_C 1e-05f
#define SLOPE 0.01f
#define EPS_C 1e-12f

#define SCAN_CHUNK 256
#define NCHUNK ((N_NODES + SCAN_CHUNK - 1) / SCAN_CHUNK)   // 391

// ---------------- ego init: concat(u_emb, i_emb) ----------------
__global__ void k_init_ego(const float* __restrict__ u_emb,
                           const float* __restrict__ i_emb,
                           float* __restrict__ ego) {
    int idx = blockIdx.x * blockDim.x + threadIdx.x;   // float4 index
    const int n4 = N_NODES * EMB / 4;
    if (idx < n4) {
        const int u4 = N_USERS * EMB / 4;
        float4 v = (idx < u4) ? ((const float4*)u_emb)[idx]
                              : ((const float4*)i_emb)[idx - u4];
        ((float4*)ego)[idx] = v;
    }
}

// ---------------- CSR build ----------------
__global__ void k_histo(const int* __restrict__ rows, int* __restrict__ counts) {
    int e = blockIdx.x * blockDim.x + threadIdx.x;
    if (e < N_EDGES) atomicAdd(&counts[rows[e]], 1);
}

__global__ void k_chunk_sum(const int* __restrict__ counts, int* __restrict__ partials) {
    __shared__ int s[SCAN_CHUNK];
    int i = blockIdx.x * SCAN_CHUNK + threadIdx.x;
    int v = (i < N_NODES) ? counts[i] : 0;
    s[threadIdx.x] = v;
    __syncthreads();
    for (int st = SCAN_CHUNK / 2; st > 0; st >>= 1) {
        if ((int)threadIdx.x < st) s[threadIdx.x] += s[threadIdx.x + st];
        __syncthreads();
    }
    if (threadIdx.x == 0) partials[blockIdx.x] = s[0];
}

__global__ void k_scan_partials(int* __restrict__ partials) {
    __shared__ int s[512];
    int t = threadIdx.x;
    int v = (t < NCHUNK) ? partials[t] : 0;
    s[t] = v;
    __syncthreads();
    for (int st = 1; st < 512; st <<= 1) {
        int add = (t >= st) ? s[t - st] : 0;
        __syncthreads();
        s[t] += add;
        __syncthreads();
    }
    if (t < NCHUNK) partials[t] = s[t] - v;   // exclusive
}

__global__ void k_chunk_scan(const int* __restrict__ counts,
                             const int* __restrict__ partials,
                             int* __restrict__ offsets,
                             int* __restrict__ cursor) {
    __shared__ int s[SCAN_CHUNK];
    int t = threadIdx.x;
    int i = blockIdx.x * SCAN_CHUNK + t;
    int v = (i < N_NODES) ? counts[i] : 0;
    s[t] = v;
    __syncthreads();
    for (int st = 1; st < SCAN_CHUNK; st <<= 1) {
        int add = (t >= st) ? s[t - st] : 0;
        __syncthreads();
        s[t] += add;
        __syncthreads();
    }
    int excl = s[t] - v + partials[blockIdx.x];
    if (i < N_NODES) { offsets[i] = excl; cursor[i] = excl; }
    if (blockIdx.x == 0 && t == 0) offsets[N_NODES] = N_EDGES;
}

__global__ void k_scatter(const int* __restrict__ rows, const int* __restrict__ cols,
                          const float* __restrict__ vals,
                          int* __restrict__ cursor,
                          int2* __restrict__ edge_cv) {
    int e = blockIdx.x * blockDim.x + threadIdx.x;
    if (e < N_EDGES) {
        int r = rows[e];
        int pos = atomicAdd(&cursor[r], 1);
        edge_cv[pos] = make_int2(cols[e], __float_as_int(vals[e]));
    }
}

// ---------------- per-layer: gather-based segment sum ----------------
// One wave per node; each QUARTER-wave (16 lanes x float4) owns one edge, so a
// single global_load_dwordx4 instruction gathers 4 edge-rows (1 KB). Edge
// metadata prefetched one iteration ahead; inactive slots use val=0 (gather
// row 0, L1-resident). Final combine: 8 shfl_xor across quarter-waves.
__global__ __launch_bounds__(256) void k_edge_agg(const int* __restrict__ offsets,
                                                  const int2* __restrict__ edge_cv,
                                                  const float* __restrict__ ego,
                                                  float* __restrict__ wsacc) {
    int n = blockIdx.x * 4 + (threadIdx.x >> 6);   // one wave per node
    int lane = threadIdx.x & 63;
    int qw = lane >> 4;     // 0..3: which edge of the group of 4
    int sl = lane & 15;     // 0..15: float4 slot within the row
    if (n >= N_NODES) return;
    int o0 = offsets[n], o1 = offsets[n + 1];
    int d = o1 - o0;
    int T = (d + 3) >> 2;
    float4 acc = make_float4(0.f, 0.f, 0.f, 0.f);
    int e = o0 + qw;
    int2 cv = (e < o1) ? edge_cv[e] : make_int2(0, 0);
    for (int t = 0; t < T; ++t) {
        int2 cur = cv;
        int en = e + 4;
        cv = (en < o1) ? edge_cv[en] : make_int2(0, 0);   // prefetch next
        float4 r = *(const float4*)&ego[(size_t)cur.x * EMB + sl * 4];
        float v = __int_as_float(cur.y);
        acc.x += v * r.x; acc.y += v * r.y;
        acc.z += v * r.z; acc.w += v * r.w;
        e = en;
    }
    acc.x += __shfl_xor(acc.x, 16, 64); acc.y += __shfl_xor(acc.y, 16, 64);
    acc.z += __shfl_xor(acc.z, 16, 64); acc.w += __shfl_xor(acc.w, 16, 64);
    acc.x += __shfl_xor(acc.x, 32, 64); acc.y += __shfl_xor(acc.y, 32, 64);
    acc.z += __shfl_xor(acc.z, 32, 64); acc.w += __shfl_xor(acc.w, 32, 64);
    if (qw == 0)
        *(float4*)&wsacc[(size_t)n * EMB + sl * 4] = acc;
}

// ---------------- per-layer transform: tiled f32 GEMM ----------------
// t = [ws | ws*ego] @ [W1^T ; W2^T] + b1 + b2 ; leaky-relu -> ego
// BM=64 rows/block, all 64 cols, K=128 split in two 64-phases.
// __launch_bounds__(256,3): cap VGPR so the K-loop (unroll 2) cannot spill;
// LDS 48KB -> 3 blocks/CU, matching.
__global__ __launch_bounds__(256, 3) void k_transform(const float* __restrict__ wsacc,
                                                      float* __restrict__ ego,
                                                      const float* __restrict__ W1,
                                                      const float* __restrict__ b1,
                                                      const float* __restrict__ W2,
                                                      const float* __restrict__ b2) {
    __shared__ float Xs[64 * 64];    // [r][k'] swizzled, one K-half at a time
    __shared__ float Ws[64 * 128];   // [c][kk'] swizzled, kk = 0..127 (W1 | W2)
    int tid = threadIdx.x;

    // stage Wcat: Ws[c][k] = W1[c][k], Ws[c][64+k] = W2[c][k]; swizzle k' = k ^ ((c>>2 & 7)<<2)
    for (int idx = tid; idx < 4096; idx += 256) {
        int c = idx >> 6, k = idx & 63;
        int s = ((c >> 2) & 7) << 2;
        Ws[c * 128 + (k ^ s)]        = W1[idx];
        Ws[c * 128 + 64 + (k ^ s)]   = W2[idx];   // (64+k)^s == 64 + (k^s)
    }

    int lane = tid & 63, wv = tid >> 6;
    int r0 = blockIdx.x * 64;
    int ty = tid >> 4;       // 0..15 : owns rows ty*4 .. ty*4+3
    int tx = tid & 15;       // 0..15 : owns cols tx*4 .. tx*4+3
    int sa = (ty & 7) << 2;  // row swizzle: (r>>2)&7 == ty&7 for r = ty*4+i
    int sb = (tx & 7) << 2;  // col-row swizzle for Ws rows c = tx*4+j

    float acc[4][4] = {};

    // ---- phase A: k = 0..63 with X = ws ----
    for (int r = wv; r < 64; r += 4) {
        float wsv = wsacc[(size_t)(r0 + r) * EMB + lane];
        int s = ((r >> 2) & 7) << 2;
        Xs[r * 64 + (lane ^ s)] = wsv;
    }
    __syncthreads();
    #pragma unroll 2
    for (int ko = 0; ko < 64; ko += 4) {
        float4 a[4], b[4];
        #pragma unroll
        for (int i = 0; i < 4; ++i)
            a[i] = *(const float4*)&Xs[(ty * 4 + i) * 64 + (ko ^ sa)];
        #pragma unroll
        for (int j = 0; j < 4; ++j)
            b[j] = *(const float4*)&Ws[(tx * 4 + j) * 128 + (ko ^ sb)];
        #pragma unroll
        for (int i = 0; i < 4; ++i)
            #pragma unroll
            for (int j = 0; j < 4; ++j)
                acc[i][j] += a[i].x * b[j].x + a[i].y * b[j].y
                           + a[i].z * b[j].z + a[i].w * b[j].w;
    }
    __syncthreads();

    // ---- phase B: k = 64..127 with X = ws*ego ----
    for (int r = wv; r < 64; r += 4) {
        size_t g = (size_t)(r0 + r) * EMB + lane;
        float v = wsacc[g] * ego[g];
        int s = ((r >> 2) & 7) << 2;
        Xs[r * 64 + (lane ^ s)] = v;
    }
    __syncthreads();
    #pragma unroll 2
    for (int ko = 0; ko < 64; ko += 4) {
        float4 a[4], b[4];
        #pragma unroll
        for (int i = 0; i < 4; ++i)
            a[i] = *(const float4*)&Xs[(ty * 4 + i) * 64 + (ko ^ sa)];
        #pragma unroll
        for (int j = 0; j < 4; ++j)
            b[j] = *(const float4*)&Ws[(tx * 4 + j) * 128 + 64 + (ko ^ sb)];
        #pragma unroll
        for (int i = 0; i < 4; ++i)
            #pragma unroll
            for (int j = 0; j < 4; ++j)
                acc[i][j] += a[i].x * b[j].x + a[i].y * b[j].y
                           + a[i].z * b[j].z + a[i].w * b[j].w;
    }

    // ---- epilogue: bias + leaky, write ego ----
    float4 bb1 = *(const float4*)&b1[tx * 4];
    float4 bb2 = *(const float4*)&b2[tx * 4];
    float bias[4] = { bb1.x + bb2.x, bb1.y + bb2.y, bb1.z + bb2.z, bb1.w + bb2.w };
    #pragma unroll
    for (int i = 0; i < 4; ++i) {
        int r = r0 + ty * 4 + i;   // < N_NODES_PAD, buffer padded -> no guard
        float4 o;
        float t0 = acc[i][0] + bias[0]; o.x = (t0 >= 0.f) ? t0 : SLOPE * t0;
        float t1 = acc[i][1] + bias[1]; o.y = (t1 >= 0.f) ? t1 : SLOPE * t1;
        float t2 = acc[i][2] + bias[2]; o.z = (t2 >= 0.f) ? t2 : SLOPE * t2;
        float t3 = acc[i][3] + bias[3]; o.w = (t3 >= 0.f) ? t3 : SLOPE * t3;
        *(float4*)&ego[(size_t)r * EMB + tx * 4] = o;
    }
}

// ---------------- per-layer: batch gather + partial-loss accumulation ----------------
// acc layout: [0]=dot_up, [1]=dot_un, [2]=ssq_u, [3]=ssq_p, [4]=ssq_n ; each [BATCH]
__global__ __launch_bounds__(256) void k_batch_acc(const float* __restrict__ src,
                                                   const int* __restrict__ u,
                                                   const int* __restrict__ ii,
                                                   const int* __restrict__ jj,
                                                   float* __restrict__ acc,
                                                   int normalize) {
    int wid = (blockIdx.x * blockDim.x + threadIdx.x) >> 6;
    int lane = threadIdx.x & 63;
    if (wid >= BATCH) return;
    int nu = u[wid];
    int np_ = N_USERS + ii[wid];
    int nn = N_USERS + jj[wid];
    float eu = src[(size_t)nu * EMB + lane];
    float ep = src[(size_t)np_ * EMB + lane];
    float en = src[(size_t)nn * EMB + lane];
    float d_up = eu * ep, d_un = eu * en;
    float s_u = eu * eu, s_p = ep * ep, s_n = en * en;
    #pragma unroll
    for (int m = 32; m > 0; m >>= 1) {
        d_up += __shfl_xor(d_up, m, 64);
        d_un += __shfl_xor(d_un, m, 64);
        s_u  += __shfl_xor(s_u,  m, 64);
        s_p  += __shfl_xor(s_p,  m, 64);
        s_n  += __shfl_xor(s_n,  m, 64);
    }
    if (lane == 0) {
        if (normalize) {
            float inu = 1.f / fmaxf(sqrtf(s_u), EPS_C);
            float inp = 1.f / fmaxf(sqrtf(s_p), EPS_C);
            float inn = 1.f / fmaxf(sqrtf(s_n), EPS_C);
            d_up *= inu * inp;
            d_un *= inu * inn;
            s_u *= inu * inu;
            s_p *= inp * inp;
            s_n *= inn * inn;
        }
        acc[0 * BATCH + wid] += d_up;
        acc[1 * BATCH + wid] += d_un;
        acc[2 * BATCH + wid] += s_u;
        acc[3 * BATCH + wid] += s_p;
        acc[4 * BATCH + wid] += s_n;
    }
}

// ---------------- final scalar ----------------
__global__ __launch_bounds__(1024) void k_finalize(const float* __restrict__ acc,
                                                   float* __restrict__ out) {
    __shared__ float s1[1024], s2[1024];
    float ls = 0.f, l2 = 0.f;
    for (int b = threadIdx.x; b < BATCH; b += 1024) {
        float x = acc[0 * BATCH + b] - acc[1 * BATCH + b];
        ls += fminf(x, 0.f) - log1pf(expf(-fabsf(x)));
        l2 += acc[2 * BATCH + b] + acc[3 * BATCH + b] + acc[4 * BATCH + b];
    }
    s1[threadIdx.x] = ls; s2[threadIdx.x] = l2;
    __syncthreads();
    for (int st = 512; st > 0; st >>= 1) {
        if ((int)threadIdx.x < st) {
            s1[threadIdx.x] += s1[threadIdx.x + st];
            s2[threadIdx.x] += s2[threadIdx.x + st];
        }
        __syncthreads();
    }
    if (threadIdx.x == 0)
        out[0] = -s1[0] / (float)BATCH + REG_C * (s2[0] * 0.5f) / (float)BATCH;
}

extern "C" void kernel_launch(void* const* d_in, const int* in_sizes, int n_in,
                              void* d_out, int out_size, void* d_ws, size_t ws_size,
                              hipStream_t stream) {
    (void)in_sizes; (void)n_in; (void)out_size; (void)ws_size;
    const int*   u     = (const int*)d_in[0];
    const int*   ii    = (const int*)d_in[1];
    const int*   jj    = (const int*)d_in[2];
    const int*   rows  = (const int*)d_in[3];
    const int*   cols  = (const int*)d_in[4];
    const float* vals  = (const float*)d_in[5];
    const float* u_emb = (const float*)d_in[6];
    const float* i_emb = (const float*)d_in[7];
    const float* W1_w  = (const float*)d_in[8];
    const float* W1_b  = (const float*)d_in[9];
    const float* W2_w  = (const float*)d_in[10];
    const float* W2_b  = (const float*)d_in[11];
    float* out = (float*)d_out;

    // workspace carve-up (rows padded to N_NODES_PAD so transform tail needs no guards)
    char* p = (char*)d_ws;
    float* ego      = (float*)p;  p += (size_t)N_NODES_PAD * EMB * 4;
    float* wsacc    = (float*)p;  p += (size_t)N_NODES_PAD * EMB * 4;
    int2*  edge_cv  = (int2*)p;   p += (size_t)N_EDGES * 8;
    int*   counts   = (int*)p;    p += (size_t)N_NODES * 4;
    int*   offsets  = (int*)p;    p += (size_t)(N_NODES + 1) * 4;
    int*   cursor   = (int*)p;    p += (size_t)N_NODES * 4;
    int*   partials = (int*)p;    p += 512 * 4;
    float* acc      = (float*)p;  p += (size_t)5 * BATCH * 4;

    hipMemsetAsync(counts, 0, (size_t)N_NODES * 4, stream);
    hipMemsetAsync(acc, 0, (size_t)5 * BATCH * 4, stream);

    k_init_ego<<<(N_NODES * EMB / 4 + 255) / 256, 256, 0, stream>>>(u_emb, i_emb, ego);
    k_histo<<<(N_EDGES + 255) / 256, 256, 0, stream>>>(rows, counts);
    k_chunk_sum<<<NCHUNK, SCAN_CHUNK, 0, stream>>>(counts, partials);
    k_scan_partials<<<1, 512, 0, stream>>>(partials);
    k_chunk_scan<<<NCHUNK, SCAN_CHUNK, 0, stream>>>(counts, partials, offsets, cursor);
    k_scatter<<<(N_EDGES + 255) / 256, 256, 0, stream>>>(rows, cols, vals, cursor, edge_cv);

    // layer 0 contribution (raw ego, no normalization)
    k_batch_acc<<<BATCH * 64 / 256, 256, 0, stream>>>(ego, u, ii, jj, acc, 0);

    for (int k = 0; k < N_LAYERS; ++k) {
        k_edge_agg<<<(N_NODES + 3) / 4, 256, 0, stream>>>(offsets, edge_cv, ego, wsacc);
        k_transform<<<(N_NODES + 63) / 64, 256, 0, stream>>>(wsacc, ego,
                                              W1_w + k * 4096, W1_b + k * 64,
                                              W2_w + k * 4096, W2_b + k * 64);
        k_batch_acc<<<BATCH * 64 / 256, 256, 0, stream>>>(ego, u, ii, jj, acc, 1);
    }
    k_finalize<<<1, 1024, 0, stream>>>(acc, out);
}